// Round 1
// baseline (292.221 us; speedup 1.0000x reference)
//
#include <hip/hip_runtime.h>

// Species-routed per-atom 3-layer MLP.
// desc [N, A, D_IN] f32, numbers [A] i32,
// W1 [S, D_IN, H], b1 [S, H], W2 [S, H, H], b2 [S, H], W3 [S, H, 1], b3 [S, 1]
// out [N, A] f32:  out[n,a] = ( silu(silu(desc[n,a]·W1[s]+b1[s])·W2[s]+b2[s]) )·W3[s] + b3[s]
// with s = numbers[a].

#define NN    4096
#define AA    256
#define DIN   39
#define HH    50
#define SS    8

__global__ __launch_bounds__(256) void atomic_mlp_f32(
    const float* __restrict__ desc,
    const int*   __restrict__ numbers,
    const float* __restrict__ W1,
    const float* __restrict__ b1,
    const float* __restrict__ W2,
    const float* __restrict__ b2,
    const float* __restrict__ W3,
    const float* __restrict__ b3,
    float*       __restrict__ out)
{
    const int a = blockIdx.x;                 // atom 0..255 (uniform per block)
    const int n = blockIdx.y * 256 + threadIdx.x;   // row 0..4095

    // Species index is block-uniform -> scalar load; all weight addresses
    // below are wave-uniform -> compiler emits s_load + v_fma with SGPR src.
    const int s = numbers[a];
    const float* __restrict__ w1  = W1 + s * (DIN * HH);
    const float* __restrict__ w2  = W2 + s * (HH * HH);
    const float* __restrict__ w3  = W3 + s * HH;
    const float* __restrict__ bb1 = b1 + s * HH;
    const float* __restrict__ bb2 = b2 + s * HH;
    const float  bias3            = b3[s];

    // Per-thread contiguous 156B desc row -> registers.
    const float* __restrict__ drow = desc + ((size_t)n * AA + a) * DIN;
    float d[DIN];
    #pragma unroll
    for (int i = 0; i < DIN; ++i) d[i] = drow[i];

    // ---- Layer 1: h1 = silu(d @ W1[s] + b1[s]) ----
    float h1[HH];
    #pragma unroll
    for (int j = 0; j < HH; ++j) h1[j] = bb1[j];

    for (int k = 0; k < DIN; ++k) {           // outer over K: weight row is
        const float x = d[k];                 // contiguous -> s_load_dwordx16
        const float* __restrict__ wr = w1 + k * HH;
        #pragma unroll
        for (int j = 0; j < HH; ++j) h1[j] = fmaf(x, wr[j], h1[j]);
    }
    #pragma unroll
    for (int j = 0; j < HH; ++j) {
        const float x = h1[j];
        h1[j] = x / (1.0f + __expf(-x));      // silu
    }

    // ---- Layer 2: h2 = silu(h1 @ W2[s] + b2[s]) ----
    float h2[HH];
    #pragma unroll
    for (int j = 0; j < HH; ++j) h2[j] = bb2[j];

    for (int k = 0; k < HH; ++k) {
        const float x = h1[k];
        const float* __restrict__ wr = w2 + k * HH;
        #pragma unroll
        for (int j = 0; j < HH; ++j) h2[j] = fmaf(x, wr[j], h2[j]);
    }

    // ---- Layer 3: out = h2 @ W3[s] + b3[s] ----
    float acc = bias3;
    #pragma unroll
    for (int j = 0; j < HH; ++j) {
        const float x = h2[j];
        acc = fmaf(x / (1.0f + __expf(-x)), w3[j], acc);
    }

    out[(size_t)n * AA + a] = acc;
}

extern "C" void kernel_launch(void* const* d_in, const int* in_sizes, int n_in,
                              void* d_out, int out_size, void* d_ws, size_t ws_size,
                              hipStream_t stream) {
    const float* desc    = (const float*)d_in[0];
    const int*   numbers = (const int*)  d_in[1];
    const float* W1      = (const float*)d_in[2];
    const float* b1      = (const float*)d_in[3];
    const float* W2      = (const float*)d_in[4];
    const float* b2      = (const float*)d_in[5];
    const float* W3      = (const float*)d_in[6];
    const float* b3      = (const float*)d_in[7];
    float*       out     = (float*)d_out;

    dim3 grid(AA, NN / 256);
    dim3 block(256);
    hipLaunchKernelGGL(atomic_mlp_f32, grid, block, 0, stream,
                       desc, numbers, W1, b1, W2, b2, W3, b3, out);
}

// Round 2
// 204.128 us; speedup vs baseline: 1.4316x; 1.4316x over previous
//
#include <hip/hip_runtime.h>

// Species-routed per-atom 3-layer MLP.
// desc [N, A, D_IN] f32, numbers [A] i32,
// W1 [S, D_IN, H], b1 [S, H], W2 [S, H, H], b2 [S, H], W3 [S, H, 1], b3 [S, 1]
// out [N, A] f32.
//
// Round 2: fully unroll all K loops so d[]/h1[]/h2[] are compile-time indexed
// (rule #20: runtime-indexed arrays -> scratch; R1 showed VGPR=72 + 378MB
// scratch writes). Weights are wave-uniform -> s_load + v_fma (v,s,v,v).

#define NN    4096
#define AA    256
#define DIN   39
#define HH    50
#define SS    8

__global__ __launch_bounds__(256) void atomic_mlp_f32(
    const float* __restrict__ desc,
    const int*   __restrict__ numbers,
    const float* __restrict__ W1,
    const float* __restrict__ b1,
    const float* __restrict__ W2,
    const float* __restrict__ b2,
    const float* __restrict__ W3,
    const float* __restrict__ b3,
    float*       __restrict__ out)
{
    const int a = blockIdx.x;                       // atom (block-uniform)
    const int n = blockIdx.y * 256 + threadIdx.x;   // row

    const int s = numbers[a];
    const float* __restrict__ w1  = W1 + s * (DIN * HH);
    const float* __restrict__ w2  = W2 + s * (HH * HH);
    const float* __restrict__ w3  = W3 + s * HH;
    const float* __restrict__ bb1 = b1 + s * HH;
    const float* __restrict__ bb2 = b2 + s * HH;
    const float  bias3            = b3[s];

    // Per-thread contiguous 156B desc row -> registers.
    const float* __restrict__ drow = desc + ((size_t)n * AA + a) * DIN;
    float d[DIN];
    #pragma unroll
    for (int i = 0; i < DIN; ++i) d[i] = drow[i];

    // ---- Layer 1: h1 = silu(d @ W1[s] + b1[s]) ----
    float h1[HH];
    #pragma unroll
    for (int j = 0; j < HH; ++j) h1[j] = bb1[j];

    #pragma unroll
    for (int k = 0; k < DIN; ++k) {                 // FULL unroll: d[k] static
        const float x = d[k];
        const float* __restrict__ wr = w1 + k * HH;
        #pragma unroll
        for (int j = 0; j < HH; ++j) h1[j] = fmaf(x, wr[j], h1[j]);
    }
    #pragma unroll
    for (int j = 0; j < HH; ++j) {
        const float x = h1[j];
        h1[j] = x / (1.0f + __expf(-x));            // silu
    }

    // ---- Layer 2: h2 = silu(h1 @ W2[s] + b2[s]) ----
    float h2[HH];
    #pragma unroll
    for (int j = 0; j < HH; ++j) h2[j] = bb2[j];

    #pragma unroll
    for (int k = 0; k < HH; ++k) {                  // FULL unroll: h1[k] static
        const float x = h1[k];
        const float* __restrict__ wr = w2 + k * HH;
        #pragma unroll
        for (int j = 0; j < HH; ++j) h2[j] = fmaf(x, wr[j], h2[j]);
    }

    // ---- Layer 3: out = silu(h2) @ W3[s] + b3[s] ----
    float acc = bias3;
    #pragma unroll
    for (int j = 0; j < HH; ++j) {
        const float x = h2[j];
        acc = fmaf(x / (1.0f + __expf(-x)), w3[j], acc);
    }

    out[(size_t)n * AA + a] = acc;
}

extern "C" void kernel_launch(void* const* d_in, const int* in_sizes, int n_in,
                              void* d_out, int out_size, void* d_ws, size_t ws_size,
                              hipStream_t stream) {
    const float* desc    = (const float*)d_in[0];
    const int*   numbers = (const int*)  d_in[1];
    const float* W1      = (const float*)d_in[2];
    const float* b1      = (const float*)d_in[3];
    const float* W2      = (const float*)d_in[4];
    const float* b2      = (const float*)d_in[5];
    const float* W3      = (const float*)d_in[6];
    const float* b3      = (const float*)d_in[7];
    float*       out     = (float*)d_out;

    dim3 grid(AA, NN / 256);
    dim3 block(256);
    hipLaunchKernelGGL(atomic_mlp_f32, grid, block, 0, stream,
                       desc, numbers, W1, b1, W2, b2, W3, b3, out);
}

// Round 3
// 196.394 us; speedup vs baseline: 1.4879x; 1.0394x over previous
//
#include <hip/hip_runtime.h>

// Species-routed per-atom 3-layer MLP.
// desc [N, A, D_IN] f32, numbers [A] i32,
// W1 [S, D_IN, H], b1 [S, H], W2 [S, H, H], b2 [S, H], W3 [S, H, 1], b3 [S, 1]
// out [N, A] f32.
//
// Round 3: R2 still spilled (VGPR=52 < 100-float live set; 73MB extra fetch +
// 35MB extra write = scratch traffic). Fix: __launch_bounds__(256,2) -> 256
// VGPR budget so h1[50]/h2[50] stay in registers. Also replace exact f32
// division in silu with v_rcp_f32 (1 ulp): 5 VALU ops vs ~13 per silu.

#define NN    4096
#define AA    256
#define DIN   39
#define HH    50
#define SS    8

__device__ __forceinline__ float fast_silu(float x) {
    // x * rcp(1 + exp(-x)); v_rcp_f32 ~1 ulp — far below the 6e-2 threshold.
    return x * __builtin_amdgcn_rcpf(1.0f + __expf(-x));
}

__global__ __launch_bounds__(256, 2) void atomic_mlp_f32(
    const float* __restrict__ desc,
    const int*   __restrict__ numbers,
    const float* __restrict__ W1,
    const float* __restrict__ b1,
    const float* __restrict__ W2,
    const float* __restrict__ b2,
    const float* __restrict__ W3,
    const float* __restrict__ b3,
    float*       __restrict__ out)
{
    const int a = blockIdx.x;                       // atom (block-uniform)
    const int n = blockIdx.y * 256 + threadIdx.x;   // row

    const int s = numbers[a];
    const float* __restrict__ w1  = W1 + s * (DIN * HH);
    const float* __restrict__ w2  = W2 + s * (HH * HH);
    const float* __restrict__ w3  = W3 + s * HH;
    const float* __restrict__ bb1 = b1 + s * HH;
    const float* __restrict__ bb2 = b2 + s * HH;
    const float  bias3            = b3[s];

    // Per-thread contiguous 156B desc row -> registers.
    const float* __restrict__ drow = desc + ((size_t)n * AA + a) * DIN;
    float d[DIN];
    #pragma unroll
    for (int i = 0; i < DIN; ++i) d[i] = drow[i];

    // ---- Layer 1: h1 = silu(d @ W1[s] + b1[s]) ----
    float h1[HH];
    #pragma unroll
    for (int j = 0; j < HH; ++j) h1[j] = bb1[j];

    #pragma unroll
    for (int k = 0; k < DIN; ++k) {                 // full unroll: static idx
        const float x = d[k];
        const float* __restrict__ wr = w1 + k * HH;
        #pragma unroll
        for (int j = 0; j < HH; ++j) h1[j] = fmaf(x, wr[j], h1[j]);
    }
    #pragma unroll
    for (int j = 0; j < HH; ++j) h1[j] = fast_silu(h1[j]);

    // ---- Layer 2: h2 = silu(h1 @ W2[s] + b2[s]) ----
    float h2[HH];
    #pragma unroll
    for (int j = 0; j < HH; ++j) h2[j] = bb2[j];

    #pragma unroll
    for (int k = 0; k < HH; ++k) {                  // full unroll: static idx
        const float x = h1[k];
        const float* __restrict__ wr = w2 + k * HH;
        #pragma unroll
        for (int j = 0; j < HH; ++j) h2[j] = fmaf(x, wr[j], h2[j]);
    }

    // ---- Layer 3: out = silu(h2) @ W3[s] + b3[s] ----
    float acc = bias3;
    #pragma unroll
    for (int j = 0; j < HH; ++j)
        acc = fmaf(fast_silu(h2[j]), w3[j], acc);

    out[(size_t)n * AA + a] = acc;
}

extern "C" void kernel_launch(void* const* d_in, const int* in_sizes, int n_in,
                              void* d_out, int out_size, void* d_ws, size_t ws_size,
                              hipStream_t stream) {
    const float* desc    = (const float*)d_in[0];
    const int*   numbers = (const int*)  d_in[1];
    const float* W1      = (const float*)d_in[2];
    const float* b1      = (const float*)d_in[3];
    const float* W2      = (const float*)d_in[4];
    const float* b2      = (const float*)d_in[5];
    const float* W3      = (const float*)d_in[6];
    const float* b3      = (const float*)d_in[7];
    float*       out     = (float*)d_out;

    dim3 grid(AA, NN / 256);
    dim3 block(256);
    hipLaunchKernelGGL(atomic_mlp_f32, grid, block, 0, stream,
                       desc, numbers, W1, b1, W2, b2, W3, b3, out);
}

// Round 4
// 118.795 us; speedup vs baseline: 2.4599x; 1.6532x over previous
//
#include <hip/hip_runtime.h>
#include <hip/hip_bf16.h>
#include <cstring>

// Species-routed per-atom 3-layer MLP via MFMA.
// Per block: atom a (grid.x), row-tile of 256 (grid.y).
// X[256x39] @ W1[39x50] -> silu -> @ W2[50x50] -> silu -> . w3[50] + b3.
// bf16 inputs / f32 accumulation on mfma_f32_16x16x32_bf16.
//
// Wave-private pipeline: after one staging barrier, each of the 4 waves owns
// 64 rows through the whole MLP (A-frags read only its own rows; H1 overwrites
// those same rows; weights are read-only) -> no further __syncthreads().

#define NN   4096
#define AA   256
#define DIN  39
#define HH   50
#define KP   64      // padded K (both layers)
#define STR  72      // LDS row stride in bf16 (144 B -> 16B-aligned b128 reads)
#define ROWS 256     // rows per block

typedef __attribute__((ext_vector_type(8))) short bf16x8;
typedef __attribute__((ext_vector_type(4))) float f32x4;

__device__ __forceinline__ float fast_silu(float x) {
    return x * __builtin_amdgcn_rcpf(1.0f + __expf(-x));
}
__device__ __forceinline__ unsigned pack_bf2(float a, float b) {
    __hip_bfloat162 h = __float22bfloat162_rn(float2{a, b});
    unsigned u; memcpy(&u, &h, 4); return u;
}
__device__ __forceinline__ unsigned short bf16b(float a) {
    __hip_bfloat16 h = __float2bfloat16(a);
    unsigned short u; memcpy(&u, &h, 2); return u;
}

__global__ __launch_bounds__(256, 2) void atomic_mlp_mfma(
    const float* __restrict__ desc,
    const int*   __restrict__ numbers,
    const float* __restrict__ W1,
    const float* __restrict__ b1,
    const float* __restrict__ W2,
    const float* __restrict__ b2,
    const float* __restrict__ W3,
    const float* __restrict__ b3,
    float*       __restrict__ out)
{
    __shared__ unsigned short Xb [ROWS * STR];  // X tile, then H1 (same rows)
    __shared__ unsigned short W1t[KP   * STR];  // W1^T: [n][k]
    __shared__ unsigned short W2t[KP   * STR];  // W2^T: [n][k]

    const int a  = blockIdx.x;
    const int n0 = blockIdx.y * ROWS;
    const int t  = threadIdx.x;
    const int s  = numbers[a];

    // ---- stage X: thread t -> row t (39 f32 -> bf16, pad to 64) ----
    {
        const float* __restrict__ drow = desc + ((size_t)(n0 + t) * AA + a) * DIN;
        unsigned* xw = (unsigned*)&Xb[t * STR];           // 36 dwords per row
        #pragma unroll
        for (int w = 0; w < 19; ++w)
            xw[w] = pack_bf2(drow[2 * w], drow[2 * w + 1]);
        xw[19] = pack_bf2(drow[38], 0.0f);
        #pragma unroll
        for (int w = 20; w < 36; ++w) xw[w] = 0u;
    }

    // ---- stage W1^T, W2^T: word idx = n*36 + w covers (k=2w, 2w+1) of col n ----
    {
        const float* __restrict__ w1g = W1 + s * (DIN * HH);
        const float* __restrict__ w2g = W2 + s * (HH * HH);
        unsigned* u1 = (unsigned*)W1t;
        unsigned* u2 = (unsigned*)W2t;
        #pragma unroll
        for (int i = 0; i < 9; ++i) {                     // 9*256 = 2304 = 64*36
            const int idx  = t + 256 * i;
            const int nrow = idx / 36;
            const int w    = idx % 36;
            const int k0   = 2 * w, k1 = 2 * w + 1;
            const bool nv  = nrow < HH;
            float a0 = (nv && k0 < DIN) ? w1g[k0 * HH + nrow] : 0.0f;
            float a1 = (nv && k1 < DIN) ? w1g[k1 * HH + nrow] : 0.0f;
            u1[idx] = pack_bf2(a0, a1);
            float c0 = (nv && k0 < HH) ? w2g[k0 * HH + nrow] : 0.0f;
            float c1 = (nv && k1 < HH) ? w2g[k1 * HH + nrow] : 0.0f;
            u2[idx] = pack_bf2(c0, c1);
        }
    }

    // ---- per-lane bias / w3 vectors (cols 16*nf + lr) ----
    const int lane = t & 63;
    const int lg   = lane >> 4;      // k-group / row-subgroup
    const int lr   = lane & 15;      // col (C layout) / row (A frag)
    const int wid  = t >> 6;
    const int wrow = wid * 64;

    float b1v[4], b2v[4], w3v[4];
    #pragma unroll
    for (int nf = 0; nf < 4; ++nf) {
        const int col = 16 * nf + lr;
        const bool v  = col < HH;
        b1v[nf] = v ? b1[s * HH + col] : 0.0f;
        b2v[nf] = v ? b2[s * HH + col] : 0.0f;
        w3v[nf] = v ? W3[s * HH + col] : 0.0f;
    }
    const float bias3 = b3[s];

    __syncthreads();   // staging complete; everything below is wave-private

    // ---- Layer 1: acc = X @ W1 ----
    f32x4 acc[4][4];
    #pragma unroll
    for (int mf = 0; mf < 4; ++mf)
        #pragma unroll
        for (int nf = 0; nf < 4; ++nf)
            acc[mf][nf] = f32x4{0.f, 0.f, 0.f, 0.f};

    #pragma unroll
    for (int ks = 0; ks < 2; ++ks) {
        const int koff = ks * 32 + 8 * lg;
        bf16x8 af[4], bfv[4];
        #pragma unroll
        for (int mf = 0; mf < 4; ++mf)
            af[mf] = *(const bf16x8*)&Xb[(wrow + 16 * mf + lr) * STR + koff];
        #pragma unroll
        for (int nf = 0; nf < 4; ++nf)
            bfv[nf] = *(const bf16x8*)&W1t[(16 * nf + lr) * STR + koff];
        #pragma unroll
        for (int mf = 0; mf < 4; ++mf)
            #pragma unroll
            for (int nf = 0; nf < 4; ++nf)
                acc[mf][nf] = __builtin_amdgcn_mfma_f32_16x16x32_bf16(
                    af[mf], bfv[nf], acc[mf][nf], 0, 0, 0);
    }

    // ---- bias + silu, write H1 back into (dead, wave-private) X rows ----
    #pragma unroll
    for (int mf = 0; mf < 4; ++mf) {
        #pragma unroll
        for (int nf = 0; nf < 4; ++nf) {
            const f32x4 v = acc[mf][nf];
            const int col = 16 * nf + lr;
            #pragma unroll
            for (int r = 0; r < 4; ++r) {
                const float h = fast_silu(v[r] + b1v[nf]);
                const int row = wrow + 16 * mf + 4 * lg + r;
                Xb[row * STR + col] = bf16b(h);
            }
        }
    }

    // ---- Layer 2: acc = H1 @ W2 ----
    #pragma unroll
    for (int mf = 0; mf < 4; ++mf)
        #pragma unroll
        for (int nf = 0; nf < 4; ++nf)
            acc[mf][nf] = f32x4{0.f, 0.f, 0.f, 0.f};

    #pragma unroll
    for (int ks = 0; ks < 2; ++ks) {
        const int koff = ks * 32 + 8 * lg;
        bf16x8 af[4], bfv[4];
        #pragma unroll
        for (int mf = 0; mf < 4; ++mf)
            af[mf] = *(const bf16x8*)&Xb[(wrow + 16 * mf + lr) * STR + koff];
        #pragma unroll
        for (int nf = 0; nf < 4; ++nf)
            bfv[nf] = *(const bf16x8*)&W2t[(16 * nf + lr) * STR + koff];
        #pragma unroll
        for (int mf = 0; mf < 4; ++mf)
            #pragma unroll
            for (int nf = 0; nf < 4; ++nf)
                acc[mf][nf] = __builtin_amdgcn_mfma_f32_16x16x32_bf16(
                    af[mf], bfv[nf], acc[mf][nf], 0, 0, 0);
    }

    // ---- Layer 3: out[row] = sum_col silu(h2 + b2) * w3 + b3 ----
    #pragma unroll
    for (int mf = 0; mf < 4; ++mf) {
        float p0 = 0.f, p1 = 0.f, p2 = 0.f, p3 = 0.f;
        #pragma unroll
        for (int nf = 0; nf < 4; ++nf) {
            const f32x4 v = acc[mf][nf];
            p0 += fast_silu(v[0] + b2v[nf]) * w3v[nf];
            p1 += fast_silu(v[1] + b2v[nf]) * w3v[nf];
            p2 += fast_silu(v[2] + b2v[nf]) * w3v[nf];
            p3 += fast_silu(v[3] + b2v[nf]) * w3v[nf];
        }
        #pragma unroll
        for (int off = 1; off < 16; off <<= 1) {          // reduce over 16 cols
            p0 += __shfl_xor(p0, off);
            p1 += __shfl_xor(p1, off);
            p2 += __shfl_xor(p2, off);
            p3 += __shfl_xor(p3, off);
        }
        if (lr < 4) {
            const float pv = (lr == 0) ? p0 : (lr == 1) ? p1 : (lr == 2) ? p2 : p3;
            const int row  = wrow + 16 * mf + 4 * lg + lr;
            out[(size_t)(n0 + row) * AA + a] = pv + bias3;
        }
    }
}

extern "C" void kernel_launch(void* const* d_in, const int* in_sizes, int n_in,
                              void* d_out, int out_size, void* d_ws, size_t ws_size,
                              hipStream_t stream) {
    const float* desc    = (const float*)d_in[0];
    const int*   numbers = (const int*)  d_in[1];
    const float* W1      = (const float*)d_in[2];
    const float* b1      = (const float*)d_in[3];
    const float* W2      = (const float*)d_in[4];
    const float* b2      = (const float*)d_in[5];
    const float* W3      = (const float*)d_in[6];
    const float* b3      = (const float*)d_in[7];
    float*       out     = (float*)d_out;

    dim3 grid(AA, NN / ROWS);
    dim3 block(256);
    hipLaunchKernelGGL(atomic_mlp_mfma, grid, block, 0, stream,
                       desc, numbers, W1, b1, W2, b2, W3, b3, out);
}

// Round 6
// 95.423 us; speedup vs baseline: 3.0624x; 1.2449x over previous
//
#include <hip/hip_runtime.h>
#include <hip/hip_bf16.h>
#include <cstring>

// Species-routed per-atom 3-layer MLP via MFMA, round 6.
// R5 + NaN fix: X LDS rows are now FULLY initialized (cols 40..55 zeroed) and
// the tail pad behind row 255 is zeroed, so the k>=40 / k>=50 junk lanes that
// multiply zero-weight rows are finite (uninit LDS can be Inf/NaN bf16 and
// 0*Inf = NaN — that was R5's failure).

#define NN   4096
#define AA   256
#define DIN  39
#define HH   50
#define ROWS 256
#define XSTR 56            // X/H1 LDS row stride (bf16), 112 B, 16B-aligned
#define WSTR 72            // weight tile row stride (bf16), 144 B
#define WPS  (2 * 64 * WSTR)   // shorts per species in Wp (= 18432 B)

typedef __attribute__((ext_vector_type(8))) short bf16x8;
typedef __attribute__((ext_vector_type(4))) float f32x4;

__device__ __forceinline__ float fast_silu(float x) {
    return x * __builtin_amdgcn_rcpf(1.0f + __expf(-x));
}
__device__ __forceinline__ unsigned pack_bf2(float a, float b) {
    __hip_bfloat162 h = __float22bfloat162_rn(float2{a, b});
    unsigned u; memcpy(&u, &h, 4); return u;
}

// ---------------- prep kernel: once per launch, 8 blocks ----------------
// Wp[s][L][n][k] bf16 (n = out col 0..63, k = 0..63, zero-padded), dword-packed.
// Bp[s][0..3][64] f32 = b1, b2, w3, b3(broadcast), zero-padded.
__global__ __launch_bounds__(256) void prep_weights(
    const float* __restrict__ W1, const float* __restrict__ b1,
    const float* __restrict__ W2, const float* __restrict__ b2,
    const float* __restrict__ W3, const float* __restrict__ b3,
    unsigned short* __restrict__ Wp, float* __restrict__ Bp)
{
    const int s = blockIdx.x;          // species
    const int t = threadIdx.x;
    const float* __restrict__ w1g = W1 + s * (DIN * HH);
    const float* __restrict__ w2g = W2 + s * (HH * HH);
    unsigned* __restrict__ out1 = (unsigned*)(Wp + (size_t)s * WPS);
    unsigned* __restrict__ out2 = out1 + 64 * (WSTR / 2);

    #pragma unroll
    for (int i = 0; i < 9; ++i) {      // 9*256 = 2304 = 64 rows * 36 dwords
        const int idx = t + 256 * i;
        const int n   = idx / 36;      // output column
        const int w   = idx % 36;      // dword within row (k pair)
        const int k0  = 2 * w, k1 = k0 + 1;
        const bool nv = n < HH;
        float a0 = (nv && k0 < DIN) ? w1g[k0 * HH + n] : 0.0f;
        float a1 = (nv && k1 < DIN) ? w1g[k1 * HH + n] : 0.0f;
        out1[idx] = pack_bf2(a0, a1);
        float c0 = (nv && k0 < HH) ? w2g[k0 * HH + n] : 0.0f;
        float c1 = (nv && k1 < HH) ? w2g[k1 * HH + n] : 0.0f;
        out2[idx] = pack_bf2(c0, c1);
    }
    if (t < 64) {
        float* bp = Bp + s * 256;
        const bool v = t < HH;
        bp[t]       = v ? b1[s * HH + t] : 0.0f;
        bp[64 + t]  = v ? b2[s * HH + t] : 0.0f;
        bp[128 + t] = v ? W3[s * HH + t] : 0.0f;
        bp[192 + t] = b3[s];
    }
}

// Pack one desc row from an aligned 11-float4 window, rotated by R dwords.
// All indices compile-time -> registers only (rule #20). Writes the FULL
// 56-short row: cols 0..39 data, cols 40..55 zeros.
template<int R>
__device__ __forceinline__ void pack_row(const float4 (&w)[11],
                                         unsigned short* __restrict__ ldsrow)
{
    const float* wf = reinterpret_cast<const float*>(&w[0]);
    uint4 o[5];
    unsigned* ow = (unsigned*)o;
    #pragma unroll
    for (int j = 0; j < 19; ++j) ow[j] = pack_bf2(wf[2 * j + R], wf[2 * j + 1 + R]);
    ow[19] = pack_bf2(wf[38 + R], 0.0f);   // k=38 valid, k=39 zero pad
    uint4* dst = (uint4*)ldsrow;           // 16B-aligned (XSTR*2 = 112)
    #pragma unroll
    for (int j = 0; j < 5; ++j) dst[j] = o[j];        // cols 0..39
    const uint4 z = uint4{0u, 0u, 0u, 0u};
    dst[5] = z;                                       // cols 40..47
    dst[6] = z;                                       // cols 48..55
}

// ---------------- main kernel ----------------
__global__ __launch_bounds__(256, 3) void atomic_mlp_mfma(
    const float* __restrict__ desc,
    const int*   __restrict__ numbers,
    const unsigned short* __restrict__ Wp,
    const float* __restrict__ Bp,
    float*       __restrict__ out)
{
    __shared__ unsigned short Xb[ROWS * XSTR + 8];  // X then H1; +8 shorts pad
    __shared__ unsigned short WT[2 * 64 * WSTR];    // W1t | W2t images

    const int a  = blockIdx.x;
    const int n0 = blockIdx.y * ROWS;
    const int t  = threadIdx.x;
    const int s  = numbers[a];

    // ---- X staging: aligned float4 window + uniform static rotate ----
    {
        const size_t g0dw = ((size_t)(n0 + t) * AA + a) * DIN;  // row start dword
        const int r = (3 * a) & 3;                  // == g0dw & 3, block-uniform
        const float* base = desc + (g0dw - (size_t)r);          // 16B-aligned
        const float4* bp4 = (const float4*)base;
        float4 w[11];
        #pragma unroll
        for (int i = 0; i < 10; ++i) w[i] = bp4[i];
        // chunk 10 only consumed when r >= 2; clamp so the final rows can't
        // read past the buffer.
        const float* lim = desc + (size_t)NN * AA * DIN - 4;
        const float* c10 = base + 40;
        w[10] = *(const float4*)(c10 <= lim ? c10 : lim);

        unsigned short* ldsrow = &Xb[t * XSTR];
        switch (r) {                                // block-uniform 4-way branch
            case 0: pack_row<0>(w, ldsrow); break;
            case 1: pack_row<1>(w, ldsrow); break;
            case 2: pack_row<2>(w, ldsrow); break;
            default: pack_row<3>(w, ldsrow); break;
        }
    }
    // zero the 8-short tail pad (row 255's koff=56 fragment reads it)
    if (t == 0) *(uint4*)&Xb[ROWS * XSTR] = uint4{0u, 0u, 0u, 0u};

    // ---- weight staging: coalesced 18 KB copy of prepped image ----
    {
        const uint4* __restrict__ src = (const uint4*)(Wp + (size_t)s * WPS);
        uint4* dst = (uint4*)WT;
        #pragma unroll
        for (int i = 0; i < 5; ++i) {
            const int idx = t + 256 * i;            // 1152 uint4 total
            if (idx < (WPS * 2) / 16) dst[idx] = src[idx];
        }
    }

    // ---- per-lane bias / w3 vectors (coalesced, padded) ----
    const int lane = t & 63;
    const int lg   = lane >> 4;      // k-group / row-subgroup
    const int lr   = lane & 15;      // col (C layout) / row (A frag)
    const int wid  = t >> 6;
    const int wrow = wid * 64;

    const float* __restrict__ bp = Bp + s * 256;
    float b1v[4], b2v[4], w3v[4];
    #pragma unroll
    for (int nf = 0; nf < 4; ++nf) {
        const int col = 16 * nf + lr;
        b1v[nf] = bp[col];
        b2v[nf] = bp[64 + col];
        w3v[nf] = bp[128 + col];
    }
    const float bias3 = bp[192];

    __syncthreads();   // staging complete; below is wave-private

    // ---- Layer 1: acc = X @ W1 ----
    f32x4 acc[4][4];
    #pragma unroll
    for (int mf = 0; mf < 4; ++mf)
        #pragma unroll
        for (int nf = 0; nf < 4; ++nf)
            acc[mf][nf] = f32x4{0.f, 0.f, 0.f, 0.f};

    #pragma unroll
    for (int ks = 0; ks < 2; ++ks) {
        const int koff = ks * 32 + 8 * lg;   // k>=40: zeros/finite x zero W rows
        bf16x8 af[4], bfv[4];
        #pragma unroll
        for (int mf = 0; mf < 4; ++mf)
            af[mf] = *(const bf16x8*)&Xb[(wrow + 16 * mf + lr) * XSTR + koff];
        #pragma unroll
        for (int nf = 0; nf < 4; ++nf)
            bfv[nf] = *(const bf16x8*)&WT[(16 * nf + lr) * WSTR + koff];
        #pragma unroll
        for (int mf = 0; mf < 4; ++mf)
            #pragma unroll
            for (int nf = 0; nf < 4; ++nf)
                acc[mf][nf] = __builtin_amdgcn_mfma_f32_16x16x32_bf16(
                    af[mf], bfv[nf], acc[mf][nf], 0, 0, 0);
    }

    // ---- bias + silu, H1 back into wave-private X rows (cols < 50 only) ----
    #pragma unroll
    for (int mf = 0; mf < 4; ++mf) {
        #pragma unroll
        for (int nf = 0; nf < 4; ++nf) {
            const f32x4 v = acc[mf][nf];
            const int col = 16 * nf + lr;
            if (col < HH) {                          // never cross row stride
                #pragma unroll
                for (int r = 0; r < 4; ++r) {
                    const float h = fast_silu(v[r] + b1v[nf]);
                    const int row = wrow + 16 * mf + 4 * lg + r;
                    __hip_bfloat16 hb = __float2bfloat16(h);
                    unsigned short u; memcpy(&u, &hb, 2);
                    Xb[row * XSTR + col] = u;
                }
            }
        }
    }

    // ---- Layer 2: acc = H1 @ W2 ----
    #pragma unroll
    for (int mf = 0; mf < 4; ++mf)
        #pragma unroll
        for (int nf = 0; nf < 4; ++nf)
            acc[mf][nf] = f32x4{0.f, 0.f, 0.f, 0.f};

    #pragma unroll
    for (int ks = 0; ks < 2; ++ks) {
        const int koff = ks * 32 + 8 * lg;   // k>=50: zeros x zero W rows
        bf16x8 af[4], bfv[4];
        #pragma unroll
        for (int mf = 0; mf < 4; ++mf)
            af[mf] = *(const bf16x8*)&Xb[(wrow + 16 * mf + lr) * XSTR + koff];
        #pragma unroll
        for (int nf = 0; nf < 4; ++nf)
            bfv[nf] = *(const bf16x8*)&WT[64 * WSTR + (16 * nf + lr) * WSTR + koff];
        #pragma unroll
        for (int mf = 0; mf < 4; ++mf)
            #pragma unroll
            for (int nf = 0; nf < 4; ++nf)
                acc[mf][nf] = __builtin_amdgcn_mfma_f32_16x16x32_bf16(
                    af[mf], bfv[nf], acc[mf][nf], 0, 0, 0);
    }

    // ---- Layer 3: out[row] = sum_col silu(h2 + b2) * w3 + b3 ----
    #pragma unroll
    for (int mf = 0; mf < 4; ++mf) {
        float p0 = 0.f, p1 = 0.f, p2 = 0.f, p3 = 0.f;
        #pragma unroll
        for (int nf = 0; nf < 4; ++nf) {
            const f32x4 v = acc[mf][nf];
            p0 += fast_silu(v[0] + b2v[nf]) * w3v[nf];
            p1 += fast_silu(v[1] + b2v[nf]) * w3v[nf];
            p2 += fast_silu(v[2] + b2v[nf]) * w3v[nf];
            p3 += fast_silu(v[3] + b2v[nf]) * w3v[nf];
        }
        #pragma unroll
        for (int off = 1; off < 16; off <<= 1) {
            p0 += __shfl_xor(p0, off);
            p1 += __shfl_xor(p1, off);
            p2 += __shfl_xor(p2, off);
            p3 += __shfl_xor(p3, off);
        }
        if (lr < 4) {
            const float pv = (lr == 0) ? p0 : (lr == 1) ? p1 : (lr == 2) ? p2 : p3;
            const int row  = wrow + 16 * mf + 4 * lg + lr;
            out[(size_t)(n0 + row) * AA + a] = pv + bias3;
        }
    }
}

extern "C" void kernel_launch(void* const* d_in, const int* in_sizes, int n_in,
                              void* d_out, int out_size, void* d_ws, size_t ws_size,
                              hipStream_t stream) {
    const float* desc    = (const float*)d_in[0];
    const int*   numbers = (const int*)  d_in[1];
    const float* W1      = (const float*)d_in[2];
    const float* b1      = (const float*)d_in[3];
    const float* W2      = (const float*)d_in[4];
    const float* b2      = (const float*)d_in[5];
    const float* W3      = (const float*)d_in[6];
    const float* b3      = (const float*)d_in[7];
    float*       out     = (float*)d_out;

    unsigned short* Wp = (unsigned short*)d_ws;              // 8*18432 B
    float*          Bp = (float*)((char*)d_ws + 8 * WPS * 2);// 8*256 f32

    hipLaunchKernelGGL(prep_weights, dim3(8), dim3(256), 0, stream,
                       W1, b1, W2, b2, W3, b3, Wp, Bp);

    dim3 grid(AA, NN / ROWS);
    hipLaunchKernelGGL(atomic_mlp_mfma, grid, dim3(256), 0, stream,
                       desc, numbers, Wp, Bp, out);
}

// Round 7
// 95.114 us; speedup vs baseline: 3.0723x; 1.0032x over previous
//
#include <hip/hip_runtime.h>
#include <hip/hip_bf16.h>
#include <cstring>

// Species-routed per-atom 3-layer MLP via MFMA, round 7.
// R6 was latency-bound at 26% occupancy (L3-resident input: replays show
// 367 GB/s HBM). Changes:
//  - weights pre-packed in per-lane MFMA B-fragment order -> loaded straight
//    to VGPRs via coalesced global_load_dwordx4 (no WT LDS, no LDS copy)
//  - LDS 47.6 -> 28.7 KB  => 4 blocks/CU (launch_bounds(256,4))
//  - W2 frag loads issued under the L1 silu-writeback to hide L2 latency
//  - prep spread over 64 blocks so its replayed cost is ~1-2 us

#define NN   4096
#define AA   256
#define DIN  39
#define HH   50
#define ROWS 256
#define XSTR 56                    // X/H1 LDS row stride (bf16): 112 B
#define WFS  (2 * 2 * 4 * 64 * 8)  // shorts per species, frag layout (16 KB)

typedef __attribute__((ext_vector_type(8))) short bf16x8;
typedef __attribute__((ext_vector_type(4))) float f32x4;

__device__ __forceinline__ float fast_silu(float x) {
    return x * __builtin_amdgcn_rcpf(1.0f + __expf(-x));
}
__device__ __forceinline__ unsigned pack_bf2(float a, float b) {
    __hip_bfloat162 h = __float22bfloat162_rn(float2{a, b});
    unsigned u; memcpy(&u, &h, 4); return u;
}

// ---------------- prep: weights -> per-lane B-frag layout ----------------
// Wf[s] dword d encodes [L][ks][nf][lane][j-pair]:
//   j2=d&3, lane=(d>>2)&63, nf=(d>>8)&3, ks=(d>>10)&1, L=(d>>11)&1
//   col = 16*nf + (lane&15), k = ks*32 + 8*(lane>>4) + 2*j2 (+1)
// Bp[s][0..3][64] f32 = b1, b2, w3, b3(broadcast), zero-padded.
__global__ __launch_bounds__(256) void prep_weights(
    const float* __restrict__ W1, const float* __restrict__ b1,
    const float* __restrict__ W2, const float* __restrict__ b2,
    const float* __restrict__ W3, const float* __restrict__ b3,
    unsigned short* __restrict__ Wf, float* __restrict__ Bp)
{
    const int s = blockIdx.x >> 3;       // species
    const int c = blockIdx.x & 7;        // chunk
    const int t = threadIdx.x;
    const float* __restrict__ w1g = W1 + s * (DIN * HH);
    const float* __restrict__ w2g = W2 + s * (HH * HH);
    unsigned* __restrict__ outw = (unsigned*)(Wf + (size_t)s * WFS);

    #pragma unroll
    for (int i = 0; i < 2; ++i) {
        const int d    = c * 512 + i * 256 + t;    // dword idx in [0,4096)
        const int j2   = d & 3;
        const int lane = (d >> 2) & 63;
        const int nf   = (d >> 8) & 3;
        const int ks   = (d >> 10) & 1;
        const int L    = (d >> 11) & 1;
        const int col  = 16 * nf + (lane & 15);
        const int k0   = ks * 32 + 8 * (lane >> 4) + 2 * j2;
        const int k1   = k0 + 1;
        float v0 = 0.f, v1 = 0.f;
        if (col < HH) {
            if (L == 0) {
                if (k0 < DIN) v0 = w1g[k0 * HH + col];
                if (k1 < DIN) v1 = w1g[k1 * HH + col];
            } else {
                if (k0 < HH)  v0 = w2g[k0 * HH + col];
                if (k1 < HH)  v1 = w2g[k1 * HH + col];
            }
        }
        outw[d] = pack_bf2(v0, v1);
    }
    if (c == 0 && t < 64) {
        float* bp = Bp + s * 256;
        const bool v = t < HH;
        bp[t]       = v ? b1[s * HH + t] : 0.0f;
        bp[64 + t]  = v ? b2[s * HH + t] : 0.0f;
        bp[128 + t] = v ? W3[s * HH + t] : 0.0f;
        bp[192 + t] = b3[s];
    }
}

// Pack one desc row from an aligned 11-float4 window, rotated by R dwords.
// All indices compile-time -> registers only. Writes the FULL 56-short row.
template<int R>
__device__ __forceinline__ void pack_row(const float4 (&w)[11],
                                         unsigned short* __restrict__ ldsrow)
{
    const float* wf = reinterpret_cast<const float*>(&w[0]);
    uint4 o[5];
    unsigned* ow = (unsigned*)o;
    #pragma unroll
    for (int j = 0; j < 19; ++j) ow[j] = pack_bf2(wf[2 * j + R], wf[2 * j + 1 + R]);
    ow[19] = pack_bf2(wf[38 + R], 0.0f);
    uint4* dst = (uint4*)ldsrow;           // 16B-aligned (XSTR*2 = 112)
    #pragma unroll
    for (int j = 0; j < 5; ++j) dst[j] = o[j];        // cols 0..39
    const uint4 z = uint4{0u, 0u, 0u, 0u};
    dst[5] = z;                                       // cols 40..47
    dst[6] = z;                                       // cols 48..55
}

// ---------------- main kernel ----------------
__global__ __launch_bounds__(256, 4) void atomic_mlp_mfma(
    const float* __restrict__ desc,
    const int*   __restrict__ numbers,
    const unsigned short* __restrict__ Wf,
    const float* __restrict__ Bp,
    float*       __restrict__ out)
{
    __shared__ unsigned short Xb[ROWS * XSTR + 8];  // X then H1; +8 shorts pad

    const int a  = blockIdx.x;
    const int n0 = blockIdx.y * ROWS;
    const int t  = threadIdx.x;
    const int s  = numbers[a];

    // ---- X staging: aligned float4 window + block-uniform static rotate ----
    {
        const size_t g0dw = ((size_t)(n0 + t) * AA + a) * DIN;
        const int r = (3 * a) & 3;                  // == g0dw & 3, block-uniform
        const float* base = desc + (g0dw - (size_t)r);
        const float4* bp4 = (const float4*)base;
        float4 w[11];
        #pragma unroll
        for (int i = 0; i < 10; ++i) w[i] = bp4[i];
        const float* lim = desc + (size_t)NN * AA * DIN - 4;
        const float* c10 = base + 40;
        w[10] = *(const float4*)(c10 <= lim ? c10 : lim);

        unsigned short* ldsrow = &Xb[t * XSTR];
        switch (r) {
            case 0: pack_row<0>(w, ldsrow); break;
            case 1: pack_row<1>(w, ldsrow); break;
            case 2: pack_row<2>(w, ldsrow); break;
            default: pack_row<3>(w, ldsrow); break;
        }
    }
    if (t == 0) *(uint4*)&Xb[ROWS * XSTR] = uint4{0u, 0u, 0u, 0u};

    const int lane = t & 63;
    const int lg   = lane >> 4;
    const int lr   = lane & 15;
    const int wid  = t >> 6;
    const int wrow = wid * 64;

    // ---- W1 B-frags straight to registers (coalesced 1KB wave-loads) ----
    const unsigned short* __restrict__ wfs = Wf + (size_t)s * WFS;
    bf16x8 w1f[2][4];
    #pragma unroll
    for (int ks = 0; ks < 2; ++ks)
        #pragma unroll
        for (int nf = 0; nf < 4; ++nf)
            w1f[ks][nf] = *(const bf16x8*)&wfs[((ks * 4 + nf) * 64 + lane) * 8];

    // ---- per-lane bias / w3 vectors (padded, from prep) ----
    const float* __restrict__ bp = Bp + s * 256;
    float b1v[4], b2v[4], w3v[4];
    #pragma unroll
    for (int nf = 0; nf < 4; ++nf) {
        const int col = 16 * nf + lr;
        b1v[nf] = bp[col];
        b2v[nf] = bp[64 + col];
        w3v[nf] = bp[128 + col];
    }
    const float bias3 = bp[192];

    __syncthreads();   // X staged; below is wave-private

    // ---- Layer 1: acc = X @ W1 ----
    f32x4 acc[4][4];
    #pragma unroll
    for (int mf = 0; mf < 4; ++mf)
        #pragma unroll
        for (int nf = 0; nf < 4; ++nf)
            acc[mf][nf] = f32x4{0.f, 0.f, 0.f, 0.f};

    #pragma unroll
    for (int ks = 0; ks < 2; ++ks) {
        const int koff = ks * 32 + 8 * lg;   // k>=40: zeros x zero-k frags
        bf16x8 af[4];
        #pragma unroll
        for (int mf = 0; mf < 4; ++mf)
            af[mf] = *(const bf16x8*)&Xb[(wrow + 16 * mf + lr) * XSTR + koff];
        #pragma unroll
        for (int mf = 0; mf < 4; ++mf)
            #pragma unroll
            for (int nf = 0; nf < 4; ++nf)
                acc[mf][nf] = __builtin_amdgcn_mfma_f32_16x16x32_bf16(
                    af[mf], w1f[ks][nf], acc[mf][nf], 0, 0, 0);
    }

    // ---- W2 frags: issue now, latency hides under the silu writeback ----
    bf16x8 w2f[2][4];
    #pragma unroll
    for (int ks = 0; ks < 2; ++ks)
        #pragma unroll
        for (int nf = 0; nf < 4; ++nf)
            w2f[ks][nf] = *(const bf16x8*)&wfs[((8 + ks * 4 + nf) * 64 + lane) * 8];

    // ---- bias + silu, H1 back into wave-private X rows (cols < 50) ----
    #pragma unroll
    for (int mf = 0; mf < 4; ++mf) {
        #pragma unroll
        for (int nf = 0; nf < 4; ++nf) {
            const f32x4 v = acc[mf][nf];
            const int col = 16 * nf + lr;
            if (col < HH) {
                #pragma unroll
                for (int r = 0; r < 4; ++r) {
                    const float h = fast_silu(v[r] + b1v[nf]);
                    const int row = wrow + 16 * mf + 4 * lg + r;
                    __hip_bfloat16 hb = __float2bfloat16(h);
                    unsigned short u; memcpy(&u, &hb, 2);
                    Xb[row * XSTR + col] = u;
                }
            }
        }
    }

    // ---- Layer 2: acc = H1 @ W2 ----
    #pragma unroll
    for (int mf = 0; mf < 4; ++mf)
        #pragma unroll
        for (int nf = 0; nf < 4; ++nf)
            acc[mf][nf] = f32x4{0.f, 0.f, 0.f, 0.f};

    #pragma unroll
    for (int ks = 0; ks < 2; ++ks) {
        const int koff = ks * 32 + 8 * lg;   // k>=50: zeros x zero-k frags
        bf16x8 af[4];
        #pragma unroll
        for (int mf = 0; mf < 4; ++mf)
            af[mf] = *(const bf16x8*)&Xb[(wrow + 16 * mf + lr) * XSTR + koff];
        #pragma unroll
        for (int mf = 0; mf < 4; ++mf)
            #pragma unroll
            for (int nf = 0; nf < 4; ++nf)
                acc[mf][nf] = __builtin_amdgcn_mfma_f32_16x16x32_bf16(
                    af[mf], w2f[ks][nf], acc[mf][nf], 0, 0, 0);
    }

    // ---- Layer 3: out[row] = sum_col silu(h2 + b2) * w3 + b3 ----
    #pragma unroll
    for (int mf = 0; mf < 4; ++mf) {
        float p0 = 0.f, p1 = 0.f, p2 = 0.f, p3 = 0.f;
        #pragma unroll
        for (int nf = 0; nf < 4; ++nf) {
            const f32x4 v = acc[mf][nf];
            p0 += fast_silu(v[0] + b2v[nf]) * w3v[nf];
            p1 += fast_silu(v[1] + b2v[nf]) * w3v[nf];
            p2 += fast_silu(v[2] + b2v[nf]) * w3v[nf];
            p3 += fast_silu(v[3] + b2v[nf]) * w3v[nf];
        }
        #pragma unroll
        for (int off = 1; off < 16; off <<= 1) {
            p0 += __shfl_xor(p0, off);
            p1 += __shfl_xor(p1, off);
            p2 += __shfl_xor(p2, off);
            p3 += __shfl_xor(p3, off);
        }
        if (lr < 4) {
            const float pv = (lr == 0) ? p0 : (lr == 1) ? p1 : (lr == 2) ? p2 : p3;
            const int row  = wrow + 16 * mf + 4 * lg + lr;
            out[(size_t)(n0 + row) * AA + a] = pv + bias3;
        }
    }
}

extern "C" void kernel_launch(void* const* d_in, const int* in_sizes, int n_in,
                              void* d_out, int out_size, void* d_ws, size_t ws_size,
                              hipStream_t stream) {
    const float* desc    = (const float*)d_in[0];
    const int*   numbers = (const int*)  d_in[1];
    const float* W1      = (const float*)d_in[2];
    const float* b1      = (const float*)d_in[3];
    const float* W2      = (const float*)d_in[4];
    const float* b2      = (const float*)d_in[5];
    const float* W3      = (const float*)d_in[6];
    const float* b3      = (const float*)d_in[7];
    float*       out     = (float*)d_out;

    unsigned short* Wf = (unsigned short*)d_ws;                  // 8*16384 B
    float*          Bp = (float*)((char*)d_ws + 8 * WFS * 2);    // 8*256 f32

    hipLaunchKernelGGL(prep_weights, dim3(64), dim3(256), 0, stream,
                       W1, b1, W2, b2, W3, b3, Wf, Bp);

    dim3 grid(AA, NN / ROWS);
    hipLaunchKernelGGL(atomic_mlp_mfma, grid, dim3(256), 0, stream,
                       desc, numbers, Wf, Bp, out);
}

// Round 8
// 71.278 us; speedup vs baseline: 4.0997x; 1.3344x over previous
//
#include <hip/hip_runtime.h>
#include <hip/hip_bf16.h>
#include <cstring>

// Species-routed per-atom 3-layer MLP via MFMA, round 8.
// Block = 4 atoms x 64 rows: for fixed n, 4 consecutive atoms are 624B
// contiguous (= exactly 39 aligned 16B chunks) -> fully coalesced staging.
// Wave w owns atom a0+w end-to-end (wave-uniform species).
// Per-mf (16-row) pipeline keeps the live set ~110 VGPR (R7 spilled:
// VGPR=64 + 40MB scratch writes with the 64-VGPR acc array).
// Output goes through LDS -> single float4 wave-store per block.

#define NN    4096
#define AA    256
#define DIN   39
#define HH    50
#define ATILE 4
#define NTILE 64
#define XSTR  56                   // X/H1 LDS row stride (bf16): 112 B
#define WFS   (2 * 2 * 4 * 64 * 8) // shorts per species, frag layout (16 KB)

typedef __attribute__((ext_vector_type(8))) short bf16x8;
typedef __attribute__((ext_vector_type(4))) float f32x4;

__device__ __forceinline__ float fast_silu(float x) {
    return x * __builtin_amdgcn_rcpf(1.0f + __expf(-x));
}
__device__ __forceinline__ unsigned pack_bf2(float a, float b) {
    __hip_bfloat162 h = __float22bfloat162_rn(float2{a, b});
    unsigned u; memcpy(&u, &h, 4); return u;
}
__device__ __forceinline__ unsigned short bf16b(float a) {
    __hip_bfloat16 h = __float2bfloat16(a);
    unsigned short u; memcpy(&u, &h, 2); return u;
}

// ---------------- prep: weights -> per-lane B-frag layout (as R7) ----------
// Wf[s] dword d = [L][ks][nf][lane][j2]: col=16*nf+(lane&15),
// k=ks*32+8*(lane>>4)+2*j2(+1); zero outside valid ranges.
// Bp[s][0..3][64] f32 = b1, b2, w3, b3(broadcast), zero-padded.
__global__ __launch_bounds__(256) void prep_weights(
    const float* __restrict__ W1, const float* __restrict__ b1,
    const float* __restrict__ W2, const float* __restrict__ b2,
    const float* __restrict__ W3, const float* __restrict__ b3,
    unsigned short* __restrict__ Wf, float* __restrict__ Bp)
{
    const int s = blockIdx.x >> 3;
    const int c = blockIdx.x & 7;
    const int t = threadIdx.x;
    const float* __restrict__ w1g = W1 + s * (DIN * HH);
    const float* __restrict__ w2g = W2 + s * (HH * HH);
    unsigned* __restrict__ outw = (unsigned*)(Wf + (size_t)s * WFS);

    #pragma unroll
    for (int i = 0; i < 2; ++i) {
        const int d    = c * 512 + i * 256 + t;
        const int j2   = d & 3;
        const int lane = (d >> 2) & 63;
        const int nf   = (d >> 8) & 3;
        const int ks   = (d >> 10) & 1;
        const int L    = (d >> 11) & 1;
        const int col  = 16 * nf + (lane & 15);
        const int k0   = ks * 32 + 8 * (lane >> 4) + 2 * j2;
        const int k1   = k0 + 1;
        float v0 = 0.f, v1 = 0.f;
        if (col < HH) {
            if (L == 0) {
                if (k0 < DIN) v0 = w1g[k0 * HH + col];
                if (k1 < DIN) v1 = w1g[k1 * HH + col];
            } else {
                if (k0 < HH)  v0 = w2g[k0 * HH + col];
                if (k1 < HH)  v1 = w2g[k1 * HH + col];
            }
        }
        outw[d] = pack_bf2(v0, v1);
    }
    if (c == 0 && t < 64) {
        float* bp = Bp + s * 256;
        const bool v = t < HH;
        bp[t]       = v ? b1[s * HH + t] : 0.0f;
        bp[64 + t]  = v ? b2[s * HH + t] : 0.0f;
        bp[128 + t] = v ? W3[s * HH + t] : 0.0f;
        bp[192 + t] = b3[s];
    }
}

// ---------------- main kernel ----------------
__global__ __launch_bounds__(256, 4) void atomic_mlp_mfma(
    const float* __restrict__ desc,
    const int*   __restrict__ numbers,
    const unsigned short* __restrict__ Wf,
    const float* __restrict__ Bp,
    float*       __restrict__ out)
{
    __shared__ unsigned short Xb[ATILE * NTILE * XSTR + 8];  // X then H1
    __shared__ float          Ob[ATILE * NTILE];             // outputs

    const int a0 = blockIdx.x * ATILE;
    const int n0 = blockIdx.y * NTILE;
    const int t  = threadIdx.x;

    // ---- X staging: fully coalesced. Segment = (row n, atoms a0..a0+3) =
    // 624B = exactly 39 aligned float4 chunks (624 = 39*16; bases 16B-aligned
    // since a0*156 = 624*bx and n*39936 are both multiples of 16).
    #pragma unroll
    for (int i = 0; i < 10; ++i) {
        const int idx = t + 256 * i;                 // chunk index
        if (idx < NTILE * 39) {                      // 2496 chunks
            const int seg = idx / 39;                // local row
            const int off = idx - 39 * seg;          // chunk within segment
            const float4 v = *(const float4*)(desc +
                ((size_t)(n0 + seg) * AA + a0) * DIN + off * 4);
            const int f0 = off * 4;                  // float index in [0,156)
            #pragma unroll
            for (int j = 0; j < 4; ++j) {
                const int f  = f0 + j;
                const int at = f / 39;               // atom 0..3
                const int d  = f - 39 * at;          // feature 0..38
                Xb[(at * NTILE + seg) * XSTR + d] = bf16b(((const float*)&v)[j]);
            }
        }
    }
    // zero-fill cols 39..55 of LDS row t; zero tail pad
    Xb[t * XSTR + 39] = 0;
    *(uint4*)&Xb[t * XSTR + 40] = uint4{0u, 0u, 0u, 0u};
    *(uint4*)&Xb[t * XSTR + 48] = uint4{0u, 0u, 0u, 0u};
    if (t == 0) *(uint4*)&Xb[ATILE * NTILE * XSTR] = uint4{0u, 0u, 0u, 0u};

    const int lane = t & 63;
    const int lg   = lane >> 4;
    const int lr   = lane & 15;
    const int wid  = t >> 6;
    const int wbase = wid * NTILE;        // this wave's LDS row base (its atom)

    // wave-uniform species -> SGPR
    const int sw = __builtin_amdgcn_readfirstlane(numbers[a0 + wid]);
    const unsigned short* __restrict__ wfs = Wf + (size_t)sw * WFS;

    // B-frags straight to registers (coalesced 1KB wave-loads, L2-resident)
    bf16x8 w1f[2][4], w2f[2][4];
    #pragma unroll
    for (int ks = 0; ks < 2; ++ks)
        #pragma unroll
        for (int nf = 0; nf < 4; ++nf) {
            w1f[ks][nf] = *(const bf16x8*)&wfs[((ks * 4 + nf) * 64 + lane) * 8];
            w2f[ks][nf] = *(const bf16x8*)&wfs[((8 + ks * 4 + nf) * 64 + lane) * 8];
        }

    const float* __restrict__ bp = Bp + sw * 256;
    float b1v[4], b2v[4], w3v[4];
    #pragma unroll
    for (int nf = 0; nf < 4; ++nf) {
        const int col = 16 * nf + lr;
        b1v[nf] = bp[col];
        b2v[nf] = bp[64 + col];
        w3v[nf] = bp[128 + col];
    }
    const float bias3 = bp[192];

    __syncthreads();   // X staged; below is wave-private until the out store

    // ---- Layer 1, per 16-row tile (small live set: 16 acc + 8 frag VGPRs) --
    #pragma unroll
    for (int mf = 0; mf < 4; ++mf) {
        const int rbase = wbase + 16 * mf;
        bf16x8 af0 = *(const bf16x8*)&Xb[(rbase + lr) * XSTR + 8 * lg];
        bf16x8 af1 = *(const bf16x8*)&Xb[(rbase + lr) * XSTR + 32 + 8 * lg];
        f32x4 a1[4];
        #pragma unroll
        for (int nf = 0; nf < 4; ++nf) a1[nf] = f32x4{0.f, 0.f, 0.f, 0.f};
        #pragma unroll
        for (int nf = 0; nf < 4; ++nf)
            a1[nf] = __builtin_amdgcn_mfma_f32_16x16x32_bf16(af0, w1f[0][nf], a1[nf], 0, 0, 0);
        #pragma unroll
        for (int nf = 0; nf < 4; ++nf)
            a1[nf] = __builtin_amdgcn_mfma_f32_16x16x32_bf16(af1, w1f[1][nf], a1[nf], 0, 0, 0);
        // bias + silu -> H1 back into this tile's rows (cols < 50)
        #pragma unroll
        for (int nf = 0; nf < 4; ++nf) {
            const int col = 16 * nf + lr;
            if (col < HH) {
                #pragma unroll
                for (int r = 0; r < 4; ++r)
                    Xb[(rbase + 4 * lg + r) * XSTR + col] =
                        bf16b(fast_silu(a1[nf][r] + b1v[nf]));
            }
        }
    }

    // ---- Layer 2 + Layer 3, per 16-row tile ----
    #pragma unroll
    for (int mf = 0; mf < 4; ++mf) {
        const int rbase = wbase + 16 * mf;
        bf16x8 af0 = *(const bf16x8*)&Xb[(rbase + lr) * XSTR + 8 * lg];
        bf16x8 af1 = *(const bf16x8*)&Xb[(rbase + lr) * XSTR + 32 + 8 * lg];
        f32x4 a2[4];
        #pragma unroll
        for (int nf = 0; nf < 4; ++nf) a2[nf] = f32x4{0.f, 0.f, 0.f, 0.f};
        #pragma unroll
        for (int nf = 0; nf < 4; ++nf)
            a2[nf] = __builtin_amdgcn_mfma_f32_16x16x32_bf16(af0, w2f[0][nf], a2[nf], 0, 0, 0);
        #pragma unroll
        for (int nf = 0; nf < 4; ++nf)
            a2[nf] = __builtin_amdgcn_mfma_f32_16x16x32_bf16(af1, w2f[1][nf], a2[nf], 0, 0, 0);

        float p0 = 0.f, p1 = 0.f, p2 = 0.f, p3 = 0.f;
        #pragma unroll
        for (int nf = 0; nf < 4; ++nf) {
            p0 += fast_silu(a2[nf][0] + b2v[nf]) * w3v[nf];
            p1 += fast_silu(a2[nf][1] + b2v[nf]) * w3v[nf];
            p2 += fast_silu(a2[nf][2] + b2v[nf]) * w3v[nf];
            p3 += fast_silu(a2[nf][3] + b2v[nf]) * w3v[nf];
        }
        #pragma unroll
        for (int off = 1; off < 16; off <<= 1) {     // reduce over 16 cols
            p0 += __shfl_xor(p0, off);
            p1 += __shfl_xor(p1, off);
            p2 += __shfl_xor(p2, off);
            p3 += __shfl_xor(p3, off);
        }
        if (lr < 4) {
            const float pv = (lr == 0) ? p0 : (lr == 1) ? p1 : (lr == 2) ? p2 : p3;
            Ob[wbase + 16 * mf + 4 * lg + lr] = pv + bias3;
        }
    }

    __syncthreads();   // Ob complete across waves

    // ---- cooperative out store: one float4 wave-store covers the block ----
    if (t < NTILE) {
        float4 o;
        o.x = Ob[0 * NTILE + t];
        o.y = Ob[1 * NTILE + t];
        o.z = Ob[2 * NTILE + t];
        o.w = Ob[3 * NTILE + t];
        *(float4*)&out[(size_t)(n0 + t) * AA + a0] = o;
    }
}

extern "C" void kernel_launch(void* const* d_in, const int* in_sizes, int n_in,
                              void* d_out, int out_size, void* d_ws, size_t ws_size,
                              hipStream_t stream) {
    const float* desc    = (const float*)d_in[0];
    const int*   numbers = (const int*)  d_in[1];
    const float* W1      = (const float*)d_in[2];
    const float* b1      = (const float*)d_in[3];
    const float* W2      = (const float*)d_in[4];
    const float* b2      = (const float*)d_in[5];
    const float* W3      = (const float*)d_in[6];
    const float* b3      = (const float*)d_in[7];
    float*       out     = (float*)d_out;

    unsigned short* Wf = (unsigned short*)d_ws;                  // 8*16384 B
    float*          Bp = (float*)((char*)d_ws + 8 * WFS * 2);    // 8*256 f32

    hipLaunchKernelGGL(prep_weights, dim3(64), dim3(256), 0, stream,
                       W1, b1, W2, b2, W3, b3, Wf, Bp);

    dim3 grid(AA / ATILE, NN / NTILE);
    hipLaunchKernelGGL(atomic_mlp_mfma, grid, dim3(256), 0, stream,
                       desc, numbers, Wf, Bp, out);
}